// Round 3
// baseline (682.325 us; speedup 1.0000x reference)
//
#include <hip/hip_runtime.h>
#include <math.h>

#define E 1280
#define NHEAD 20
#define HD 64
#define NBLK 7
#define NBATCH 64
#define NUNIT (NBATCH * NHEAD)   // 1280 attention units
#define NTILE_O (E / 16)         // 80 o-proj tiles

typedef __bf16 bf16x8 __attribute__((ext_vector_type(8)));
typedef float floatx4 __attribute__((ext_vector_type(4)));

__device__ __forceinline__ float wave_max64(float v) {
#pragma unroll
    for (int o = 32; o > 0; o >>= 1) v = fmaxf(v, __shfl_xor(v, o, 64));
    return v;
}
__device__ __forceinline__ float wave_sum64(float v) {
#pragma unroll
    for (int o = 32; o > 0; o >>= 1) v += __shfl_xor(v, o, 64);
    return v;
}
__device__ __forceinline__ bf16x8 cvt8(float4 lo, float4 hi) {
    bf16x8 r;
    r[0] = (__bf16)lo.x; r[1] = (__bf16)lo.y; r[2] = (__bf16)lo.z; r[3] = (__bf16)lo.w;
    r[4] = (__bf16)hi.x; r[5] = (__bf16)hi.y; r[6] = (__bf16)hi.z; r[7] = (__bf16)hi.w;
    return r;
}

// ---- QKV projection: C[row][jg0+j] = (sum_k A[row][k]*Wp[j][k] + b[j]) * scl ----
// 64x16 tile/block, 4 waves, wave-split-K (320 each), no LDS in K-loop
// (fragments are contiguous 32B runs in global), depth-2 register pipeline.
// Block 0 also zero-inits the sync words for the fused attn+oproj kernel.
__global__ __launch_bounds__(256) void qkv_gemm(
    const float* __restrict__ A,
    const float* __restrict__ W0, const float* __restrict__ W1,
    const float* __restrict__ W2,
    const float* __restrict__ b0, const float* __restrict__ b1,
    const float* __restrict__ b2,
    float* __restrict__ C, int* __restrict__ sync)
{
    __shared__ __align__(16) float Cred[4][64][16];   // 16 KB

    if (blockIdx.x == 0 && threadIdx.x == 0) { sync[0] = 0; sync[1] = 0; }

    const int t = threadIdx.x;
    const int lane = t & 63;
    const int wv = t >> 6;
    const int quad = lane >> 4;
    const int l16 = lane & 15;
    const int jg0 = blockIdx.x * 16;

    const int msel = jg0 / E;
    const int j0 = jg0 - msel * E;
    const float* Wp = (msel == 0) ? W0 : ((msel == 1) ? W1 : W2);
    const float* bp = (msel == 0) ? b0 : ((msel == 1) ? b1 : b2);
    const float scl = (msel == 0) ? 0.125f : 1.0f;

    const int kbeg = wv * (E / 4);    // 320 per wave
    const int ko = quad * 8;          // fragment k-offset within 64-chunk

    const float* __restrict__ wrow = Wp + (size_t)(j0 + l16) * E;
    const float* __restrict__ arow = A + (size_t)l16 * E;

    floatx4 acc[4] = {};
    float4 Ac[16], Wc[4];

    {   // chunk 0 preload
        const int k0 = kbeg;
#pragma unroll
        for (int rg = 0; rg < 4; ++rg) {
            const float* ar = arow + (size_t)rg * 16 * E + k0 + ko;
            Ac[rg * 4 + 0] = *(const float4*)(ar);
            Ac[rg * 4 + 1] = *(const float4*)(ar + 4);
            Ac[rg * 4 + 2] = *(const float4*)(ar + 32);
            Ac[rg * 4 + 3] = *(const float4*)(ar + 36);
        }
        const float* wr = wrow + k0 + ko;
        Wc[0] = *(const float4*)(wr);
        Wc[1] = *(const float4*)(wr + 4);
        Wc[2] = *(const float4*)(wr + 32);
        Wc[3] = *(const float4*)(wr + 36);
    }

#pragma unroll
    for (int c = 0; c < 5; ++c) {
        float4 An[16], Wn[4];
        if (c < 4) {
            const int k1 = kbeg + (c + 1) * 64;
#pragma unroll
            for (int rg = 0; rg < 4; ++rg) {
                const float* ar = arow + (size_t)rg * 16 * E + k1 + ko;
                An[rg * 4 + 0] = *(const float4*)(ar);
                An[rg * 4 + 1] = *(const float4*)(ar + 4);
                An[rg * 4 + 2] = *(const float4*)(ar + 32);
                An[rg * 4 + 3] = *(const float4*)(ar + 36);
            }
            const float* wr = wrow + k1 + ko;
            Wn[0] = *(const float4*)(wr);
            Wn[1] = *(const float4*)(wr + 4);
            Wn[2] = *(const float4*)(wr + 32);
            Wn[3] = *(const float4*)(wr + 36);
        }
        const bf16x8 bf0 = cvt8(Wc[0], Wc[1]);
        const bf16x8 bf1 = cvt8(Wc[2], Wc[3]);
#pragma unroll
        for (int rg = 0; rg < 4; ++rg) {
            acc[rg] = __builtin_amdgcn_mfma_f32_16x16x32_bf16(
                cvt8(Ac[rg * 4 + 0], Ac[rg * 4 + 1]), bf0, acc[rg], 0, 0, 0);
            acc[rg] = __builtin_amdgcn_mfma_f32_16x16x32_bf16(
                cvt8(Ac[rg * 4 + 2], Ac[rg * 4 + 3]), bf1, acc[rg], 0, 0, 0);
        }
        if (c < 4) {
#pragma unroll
            for (int i = 0; i < 16; ++i) Ac[i] = An[i];
#pragma unroll
            for (int i = 0; i < 4; ++i) Wc[i] = Wn[i];
        }
    }

    // cross-wave K-reduction; C/D layout: col = lane&15, row = quad*4 + reg
#pragma unroll
    for (int rg = 0; rg < 4; ++rg)
#pragma unroll
        for (int r = 0; r < 4; ++r)
            Cred[wv][rg * 16 + quad * 4 + r][l16] = acc[rg][r];
    __syncthreads();
#pragma unroll
    for (int i = 0; i < 4; ++i) {
        const int e = t + i * 256;
        const int row = e >> 4, col = e & 15;
        float s = Cred[0][row][col] + Cred[1][row][col]
                + Cred[2][row][col] + Cred[3][row][col];
        C[(size_t)row * (3 * E) + jg0 + col] = (s + bp[j0 + col]) * scl;
    }
}

// ---- fused attention + o-proj, one dispatch ----
// Blocks [0, NUNIT): flash attention for (b,h); on completion each block
// arrives at sync[0] (atomicAdd); the 1280th arrival release-stores sync[1]=1.
// Blocks [NUNIT, NUNIT+NTILE_O): prefetch their W chunk-0, acquire-spin on
// sync[1], then run the o-proj GEMM tile reading ob. Deadlock-free by
// construction: 80 spinners can never exhaust CU slots, attn blocks wait on
// nothing. sync words are zeroed by the preceding qkv_gemm dispatch.
__global__ __launch_bounds__(256, 4) void attn_oproj(
    const float* __restrict__ qkv,
    const float* __restrict__ kcache, const float* __restrict__ vcache,
    const int* __restrict__ cache_position, const int* __restrict__ block_tables,
    float* __restrict__ ob,
    const float* __restrict__ wo, const float* __restrict__ bo,
    float* __restrict__ out, int* __restrict__ sync)
{
    __shared__ __align__(16) float smem[4096];   // 16 KB, branch-aliased

    const int t = threadIdx.x;
    const int lane = t & 63;
    const int wv = t >> 6;

    if (blockIdx.x < NUNIT) {
        // ================= attention unit =================
        float* q_lds = smem;                         // [64]
        float (*o_lds)[64] = (float (*)[64])(smem + 64);
        float* ml_lds = smem + 64 + 256;             // [4][2]

        const int bh = blockIdx.x;
        const int b = bh / NHEAD;
        const int h = bh - b * NHEAD;
        const int d4 = lane & 15;        // float4 group in d
        const int sg = lane >> 4;        // slot subgroup

        const int pos = cache_position[b];
        const int last = pos - 1;
        const int col = h * HD + lane;

        const float qd  = qkv[(size_t)b * (3 * E) + col];
        const float knd = qkv[(size_t)b * (3 * E) + E + col];
        const float vnd = qkv[(size_t)b * (3 * E) + 2 * E + col];
        if (wv == 0) q_lds[lane] = qd;
        __syncthreads();

        float m = -INFINITY, lsum = 0.0f;
        float4 vacc = make_float4(0.f, 0.f, 0.f, 0.f);

        const int nb0 = wv;
        const int nb1 = wv + 4;
        const bool hasb0 = (nb0 * 64 <= last);
        const bool hasb1 = (nb1 * 64 <= last);   // nb1<=6 when true -> no OOB

        if (hasb0) {
            const size_t bhoff = (size_t)(b * NHEAD + h) * NBLK;
            const int phys0 = block_tables[b * NBLK + nb0];
            const float* __restrict__ Kb0 = kcache + ((bhoff + phys0) << 12);
            const float* __restrict__ Vb0 = vcache + ((bhoff + phys0) << 12);
            const float* __restrict__ Kb1 = Kb0;
            const float* __restrict__ Vb1 = Vb0;
            if (hasb1) {
                const int phys1 = block_tables[b * NBLK + nb1];
                Kb1 = kcache + ((bhoff + phys1) << 12);
                Vb1 = vcache + ((bhoff + phys1) << 12);
            }

            // scores (lane = slot); split accumulators halve the dep chain
            float sc0 = 0.0f, sc1 = -INFINITY;
            {
                const float4* Krow = (const float4*)(Kb0 + lane * HD);
                float sa = 0.f, sb = 0.f;
#pragma unroll
                for (int dd = 0; dd < 16; dd += 2) {
                    float4 k4 = Krow[dd],     q4 = ((const float4*)q_lds)[dd];
                    float4 k5 = Krow[dd + 1], q5 = ((const float4*)q_lds)[dd + 1];
                    sa = fmaf(k4.x, q4.x, sa); sa = fmaf(k4.y, q4.y, sa);
                    sa = fmaf(k4.z, q4.z, sa); sa = fmaf(k4.w, q4.w, sa);
                    sb = fmaf(k5.x, q5.x, sb); sb = fmaf(k5.y, q5.y, sb);
                    sb = fmaf(k5.z, q5.z, sb); sb = fmaf(k5.w, q5.w, sb);
                }
                sc0 = sa + sb;
                if (nb0 * 64 + lane > last) sc0 = -INFINITY;
            }
            if (hasb1) {
                const float4* Krow = (const float4*)(Kb1 + lane * HD);
                float sa = 0.f, sb = 0.f;
#pragma unroll
                for (int dd = 0; dd < 16; dd += 2) {
                    float4 k4 = Krow[dd],     q4 = ((const float4*)q_lds)[dd];
                    float4 k5 = Krow[dd + 1], q5 = ((const float4*)q_lds)[dd + 1];
                    sa = fmaf(k4.x, q4.x, sa); sa = fmaf(k4.y, q4.y, sa);
                    sa = fmaf(k4.z, q4.z, sa); sa = fmaf(k4.w, q4.w, sa);
                    sb = fmaf(k5.x, q5.x, sb); sb = fmaf(k5.y, q5.y, sb);
                    sb = fmaf(k5.z, q5.z, sb); sb = fmaf(k5.w, q5.w, sb);
                }
                sc1 = (nb1 * 64 + lane > last) ? -INFINITY : (sa + sb);
            }

            // prefetch V0; loads overlap the shuffle reductions
            float4 v0r[16];
#pragma unroll
            for (int j = 0; j < 16; ++j)
                v0r[j] = *(const float4*)&Vb0[(sg + 4 * j) * HD + d4 * 4];

            // single-pass softmax over both blocks (m_ finite: slot nb0*64 valid)
            const float m_ = wave_max64(fmaxf(sc0, sc1));
            const float p0 = __expf(sc0 - m_);
            const float p1 = __expf(sc1 - m_);
            lsum = wave_sum64(p0 + p1);
            m = m_;

#pragma unroll
            for (int j = 0; j < 16; ++j) {
                const float ps = __shfl(p0, sg + 4 * j, 64);
                vacc.x = fmaf(ps, v0r[j].x, vacc.x);
                vacc.y = fmaf(ps, v0r[j].y, vacc.y);
                vacc.z = fmaf(ps, v0r[j].z, vacc.z);
                vacc.w = fmaf(ps, v0r[j].w, vacc.w);
            }
            if (hasb1) {
#pragma unroll
                for (int j = 0; j < 16; ++j) {
                    const int s = sg + 4 * j;
                    const float ps = __shfl(p1, s, 64);
                    float4 v4 = *(const float4*)&Vb1[s * HD + d4 * 4];
                    vacc.x = fmaf(ps, v4.x, vacc.x);
                    vacc.y = fmaf(ps, v4.y, vacc.y);
                    vacc.z = fmaf(ps, v4.z, vacc.z);
                    vacc.w = fmaf(ps, v4.w, vacc.w);
                }
            }
        }

        // reduce vacc over the 4 slot subgroups
#pragma unroll
        for (int o = 16; o <= 32; o <<= 1) {
            vacc.x += __shfl_xor(vacc.x, o, 64);
            vacc.y += __shfl_xor(vacc.y, o, 64);
            vacc.z += __shfl_xor(vacc.z, o, 64);
            vacc.w += __shfl_xor(vacc.w, o, 64);
        }
        if (sg == 0) *(float4*)&o_lds[wv][d4 * 4] = vacc;
        if (lane == 0) { ml_lds[wv * 2 + 0] = m; ml_lds[wv * 2 + 1] = lsum; }
        __syncthreads();

        if (wv == 0) {
            const float qk = wave_sum64(qd * knd);   // new-token score (finite)
            float Mf = qk;
#pragma unroll
            for (int w = 0; w < 4; ++w) Mf = fmaxf(Mf, ml_lds[w * 2]);
            float osum = 0.0f, Ls = 0.0f;
#pragma unroll
            for (int w = 0; w < 4; ++w) {
                const float f = __expf(ml_lds[w * 2] - Mf);   // 0 for empty waves
                osum = fmaf(o_lds[w][lane], f, osum);
                Ls   = fmaf(ml_lds[w * 2 + 1], f, Ls);
            }
            const float pn = __expf(qk - Mf);
            osum = fmaf(pn, vnd, osum);
            Ls += pn;
            ob[(size_t)b * E + h * HD + lane] = osum / Ls;
        }

        // arrival: publish ob writes, 1280th arrival releases the flag
        __threadfence();
        __syncthreads();
        if (t == 0) {
            if (__hip_atomic_fetch_add(&sync[0], 1, __ATOMIC_ACQ_REL,
                                       __HIP_MEMORY_SCOPE_AGENT) == NUNIT - 1)
                __hip_atomic_store(&sync[1], 1, __ATOMIC_RELEASE,
                                   __HIP_MEMORY_SCOPE_AGENT);
        }
        return;
    }

    // ================= o-proj tile =================
    const int jg0 = (blockIdx.x - NUNIT) * 16;
    const int quad = lane >> 4;
    const int l16 = lane & 15;
    const int kbeg = wv * (E / 4);
    const int ko = quad * 8;
    const float* __restrict__ wrow = wo + (size_t)(jg0 + l16) * E;

    // prefetch W chunk 0 while attention still runs
    float4 Wc[4];
    {
        const float* wr = wrow + kbeg + ko;
        Wc[0] = *(const float4*)(wr);
        Wc[1] = *(const float4*)(wr + 4);
        Wc[2] = *(const float4*)(wr + 32);
        Wc[3] = *(const float4*)(wr + 36);
    }

    while (__hip_atomic_load(&sync[1], __ATOMIC_ACQUIRE,
                             __HIP_MEMORY_SCOPE_AGENT) == 0)
        __builtin_amdgcn_s_sleep(8);

    floatx4 acc[4] = {};
#pragma unroll
    for (int c = 0; c < 5; ++c) {
        float4 Wn[4];
        if (c < 4) {
            const float* wr = wrow + kbeg + (c + 1) * 64 + ko;
            Wn[0] = *(const float4*)(wr);
            Wn[1] = *(const float4*)(wr + 4);
            Wn[2] = *(const float4*)(wr + 32);
            Wn[3] = *(const float4*)(wr + 36);
        }
        const bf16x8 bf0 = cvt8(Wc[0], Wc[1]);
        const bf16x8 bf1 = cvt8(Wc[2], Wc[3]);
        const int k0 = kbeg + c * 64 + ko;
#pragma unroll
        for (int rg = 0; rg < 4; ++rg) {
            const float* ar = ob + (size_t)(rg * 16 + l16) * E + k0;
            float4 a0 = *(const float4*)(ar);
            float4 a1 = *(const float4*)(ar + 4);
            float4 a2 = *(const float4*)(ar + 32);
            float4 a3 = *(const float4*)(ar + 36);
            acc[rg] = __builtin_amdgcn_mfma_f32_16x16x32_bf16(
                cvt8(a0, a1), bf0, acc[rg], 0, 0, 0);
            acc[rg] = __builtin_amdgcn_mfma_f32_16x16x32_bf16(
                cvt8(a2, a3), bf1, acc[rg], 0, 0, 0);
        }
        if (c < 4) {
#pragma unroll
            for (int i = 0; i < 4; ++i) Wc[i] = Wn[i];
        }
    }

    float (*Cred)[64][16] = (float (*)[64][16])smem;
#pragma unroll
    for (int rg = 0; rg < 4; ++rg)
#pragma unroll
        for (int r = 0; r < 4; ++r)
            Cred[wv][rg * 16 + quad * 4 + r][l16] = acc[rg][r];
    __syncthreads();
#pragma unroll
    for (int i = 0; i < 4; ++i) {
        const int e = t + i * 256;
        const int row = e >> 4, ccol = e & 15;
        float s = Cred[0][row][ccol] + Cred[1][row][ccol]
                + Cred[2][row][ccol] + Cred[3][row][ccol];
        out[(size_t)row * E + jg0 + ccol] = s + bo[jg0 + ccol];
    }
}

extern "C" void kernel_launch(void* const* d_in, const int* in_sizes, int n_in,
                              void* d_out, int out_size, void* d_ws, size_t ws_size,
                              hipStream_t stream) {
    const float* hidden = (const float*)d_in[0];
    const float* kcache = (const float*)d_in[1];
    const float* vcache = (const float*)d_in[2];
    const float* wq = (const float*)d_in[3];
    const float* bq = (const float*)d_in[4];
    const float* wk = (const float*)d_in[5];
    const float* bk = (const float*)d_in[6];
    const float* wvp = (const float*)d_in[7];
    const float* bv = (const float*)d_in[8];
    const float* wo = (const float*)d_in[9];
    const float* bo = (const float*)d_in[10];
    const int* cpos = (const int*)d_in[11];
    const int* btab = (const int*)d_in[12];
    float* out = (float*)d_out;

    // ws layout: qkv 64x3840 | ob 64x1280 | sync[2]  (≈1.31 MB, proven safe)
    float* ws = (float*)d_ws;
    float* qkv = ws;
    float* ob  = ws + 64 * 3 * E;
    int* sync  = (int*)(ws + 64 * 3 * E + 64 * E);

    // node 1: fused QKV projection (also zero-inits sync words)
    qkv_gemm<<<(3 * E) / 16, 256, 0, stream>>>(
        hidden, wq, wk, wvp, bq, bk, bv, qkv, sync);
    // node 2: attention + flag-released o-proj in one dispatch
    attn_oproj<<<NUNIT + NTILE_O, 256, 0, stream>>>(
        qkv, kcache, vcache, cpos, btab, ob, wo, bo, out, sync);
}

// Round 4
// 377.273 us; speedup vs baseline: 1.8086x; 1.8086x over previous
//
#include <hip/hip_runtime.h>
#include <math.h>

#define E 1280
#define NHEAD 20
#define HD 64
#define NBLK 7
#define NBATCH 64
#define NUNIT (NBATCH * NHEAD)   // 1280 attention units

typedef __bf16 bf16x8 __attribute__((ext_vector_type(8)));
typedef float floatx4 __attribute__((ext_vector_type(4)));

__device__ __forceinline__ float wave_max64(float v) {
#pragma unroll
    for (int o = 32; o > 0; o >>= 1) v = fmaxf(v, __shfl_xor(v, o, 64));
    return v;
}
__device__ __forceinline__ float wave_sum64(float v) {
#pragma unroll
    for (int o = 32; o > 0; o >>= 1) v += __shfl_xor(v, o, 64);
    return v;
}
__device__ __forceinline__ bf16x8 cvt8(float4 lo, float4 hi) {
    bf16x8 r;
    r[0] = (__bf16)lo.x; r[1] = (__bf16)lo.y; r[2] = (__bf16)lo.z; r[3] = (__bf16)lo.w;
    r[4] = (__bf16)hi.x; r[5] = (__bf16)hi.y; r[6] = (__bf16)hi.z; r[7] = (__bf16)hi.w;
    return r;
}

// ---- QKV projection: qkv[row][jg0+j] = (sum_k A[row][k]*Wp[j][k] + b[j]) * scl
// 64x16 tile/block, 4 waves, wave-split-K (320 each), no LDS in K-loop
// (fragments are contiguous 32B runs in global), depth-2 register pipeline.
// Blocks 0..79 additionally bias-initialize `out` (stream-orders before the
// attention dispatch's atomic accumulation). NO device-scope fences anywhere:
// round-1/round-3 showed per-block agent-scope release costs ~0.34 us each.
__global__ __launch_bounds__(256) void qkv_gemm(
    const float* __restrict__ A,
    const float* __restrict__ W0, const float* __restrict__ W1,
    const float* __restrict__ W2,
    const float* __restrict__ b0, const float* __restrict__ b1,
    const float* __restrict__ b2,
    float* __restrict__ C,
    const float* __restrict__ bo, float* __restrict__ out)
{
    __shared__ __align__(16) float Cred[4][64][16];   // 16 KB

    const int t = threadIdx.x;

    // bias-init of out: 80 blocks x 256 threads x 1 float4 = 81920 floats
    if (blockIdx.x < 80) {
        const int flat4 = blockIdx.x * 256 + t;
        const int j4 = flat4 % (E / 4);
        ((float4*)out)[flat4] = ((const float4*)bo)[j4];
    }

    const int lane = t & 63;
    const int wv = t >> 6;
    const int quad = lane >> 4;
    const int l16 = lane & 15;
    const int jg0 = blockIdx.x * 16;

    const int msel = jg0 / E;
    const int j0 = jg0 - msel * E;
    const float* Wp = (msel == 0) ? W0 : ((msel == 1) ? W1 : W2);
    const float* bp = (msel == 0) ? b0 : ((msel == 1) ? b1 : b2);
    const float scl = (msel == 0) ? 0.125f : 1.0f;

    const int kbeg = wv * (E / 4);    // 320 per wave
    const int ko = quad * 8;          // fragment k-offset within 64-chunk

    const float* __restrict__ wrow = Wp + (size_t)(j0 + l16) * E;
    const float* __restrict__ arow = A + (size_t)l16 * E;

    floatx4 acc[4] = {};
    float4 Ac[16], Wc[4];

    {   // chunk 0 preload
        const int k0 = kbeg;
#pragma unroll
        for (int rg = 0; rg < 4; ++rg) {
            const float* ar = arow + (size_t)rg * 16 * E + k0 + ko;
            Ac[rg * 4 + 0] = *(const float4*)(ar);
            Ac[rg * 4 + 1] = *(const float4*)(ar + 4);
            Ac[rg * 4 + 2] = *(const float4*)(ar + 32);
            Ac[rg * 4 + 3] = *(const float4*)(ar + 36);
        }
        const float* wr = wrow + k0 + ko;
        Wc[0] = *(const float4*)(wr);
        Wc[1] = *(const float4*)(wr + 4);
        Wc[2] = *(const float4*)(wr + 32);
        Wc[3] = *(const float4*)(wr + 36);
    }

#pragma unroll
    for (int c = 0; c < 5; ++c) {
        float4 An[16], Wn[4];
        if (c < 4) {   // issue next chunk's loads before touching current
            const int k1 = kbeg + (c + 1) * 64;
#pragma unroll
            for (int rg = 0; rg < 4; ++rg) {
                const float* ar = arow + (size_t)rg * 16 * E + k1 + ko;
                An[rg * 4 + 0] = *(const float4*)(ar);
                An[rg * 4 + 1] = *(const float4*)(ar + 4);
                An[rg * 4 + 2] = *(const float4*)(ar + 32);
                An[rg * 4 + 3] = *(const float4*)(ar + 36);
            }
            const float* wr = wrow + k1 + ko;
            Wn[0] = *(const float4*)(wr);
            Wn[1] = *(const float4*)(wr + 4);
            Wn[2] = *(const float4*)(wr + 32);
            Wn[3] = *(const float4*)(wr + 36);
        }
        const bf16x8 bf0 = cvt8(Wc[0], Wc[1]);
        const bf16x8 bf1 = cvt8(Wc[2], Wc[3]);
#pragma unroll
        for (int rg = 0; rg < 4; ++rg) {
            acc[rg] = __builtin_amdgcn_mfma_f32_16x16x32_bf16(
                cvt8(Ac[rg * 4 + 0], Ac[rg * 4 + 1]), bf0, acc[rg], 0, 0, 0);
            acc[rg] = __builtin_amdgcn_mfma_f32_16x16x32_bf16(
                cvt8(Ac[rg * 4 + 2], Ac[rg * 4 + 3]), bf1, acc[rg], 0, 0, 0);
        }
        if (c < 4) {
#pragma unroll
            for (int i = 0; i < 16; ++i) Ac[i] = An[i];
#pragma unroll
            for (int i = 0; i < 4; ++i) Wc[i] = Wn[i];
        }
    }

    // cross-wave K-reduction; C/D layout: col = lane&15, row = quad*4 + reg
#pragma unroll
    for (int rg = 0; rg < 4; ++rg)
#pragma unroll
        for (int r = 0; r < 4; ++r)
            Cred[wv][rg * 16 + quad * 4 + r][l16] = acc[rg][r];
    __syncthreads();
#pragma unroll
    for (int i = 0; i < 4; ++i) {
        const int e = t + i * 256;
        const int row = e >> 4, col = e & 15;
        float s = Cred[0][row][col] + Cred[1][row][col]
                + Cred[2][row][col] + Cred[3][row][col];
        C[(size_t)row * (3 * E) + jg0 + col] = (s + bp[j0 + col]) * scl;
    }
}

// ---- attention + algebraic o-proj, one block per (b,h), 4 waves ----
// Flash attention (single-pass softmax per wave over its <=2 KV blocks,
// cross-wave combine via LDS m/l), then the block's rank-64 o-proj
// contribution out[b][:] += o_vec . Wo[:, h*64:h*64+64]^T via relaxed
// fire-and-forget atomicAdd (no fences / flags — stream handles ordering,
// kernel-completion makes the adds visible).
__global__ __launch_bounds__(256) void attn_oproj(
    const float* __restrict__ qkv,
    const float* __restrict__ kcache, const float* __restrict__ vcache,
    const int* __restrict__ cache_position, const int* __restrict__ block_tables,
    const float* __restrict__ wo,
    float* __restrict__ out)
{
    __shared__ __align__(16) float q_lds[64];
    __shared__ __align__(16) float o_lds[4][64];
    __shared__ __align__(16) float o_final[64];
    __shared__ float ml_lds[8];

    const int bh = blockIdx.x;
    const int b = bh / NHEAD;
    const int h = bh - b * NHEAD;
    const int t = threadIdx.x;
    const int lane = t & 63;
    const int wv = t >> 6;
    const int d4 = lane & 15;        // float4 group in d
    const int sg = lane >> 4;        // slot subgroup

    const int pos = cache_position[b];
    const int last = pos - 1;
    const int col = h * HD + lane;

    const float qd  = qkv[(size_t)b * (3 * E) + col];
    const float knd = qkv[(size_t)b * (3 * E) + E + col];
    const float vnd = qkv[(size_t)b * (3 * E) + 2 * E + col];
    if (wv == 0) q_lds[lane] = qd;
    __syncthreads();

    float m = -INFINITY, lsum = 0.0f;
    float4 vacc = make_float4(0.f, 0.f, 0.f, 0.f);

    const int nb0 = wv;
    const int nb1 = wv + 4;
    const bool hasb0 = (nb0 * 64 <= last);
    const bool hasb1 = (nb1 * 64 <= last);   // nb1<=6 when true -> no OOB

    if (hasb0) {
        const int ll0 = last - nb0 * 64;     // last valid slot in block 0 (>=0)
        const int ll1 = last - nb1 * 64;     // may be <0 when !hasb1
        const size_t bhoff = (size_t)(b * NHEAD + h) * NBLK;
        const int phys0 = block_tables[b * NBLK + nb0];
        const float* __restrict__ Kb0 = kcache + ((bhoff + phys0) << 12);
        const float* __restrict__ Vb0 = vcache + ((bhoff + phys0) << 12);
        const float* __restrict__ Kb1 = Kb0;
        const float* __restrict__ Vb1 = Vb0;
        if (hasb1) {
            const int phys1 = block_tables[b * NBLK + nb1];
            Kb1 = kcache + ((bhoff + phys1) << 12);
            Vb1 = vcache + ((bhoff + phys1) << 12);
        }

        // scores (lane = slot); masked lanes skip the K-row read entirely
        float sc0 = -INFINITY, sc1 = -INFINITY;
        if (lane <= ll0) {
            const float4* Krow = (const float4*)(Kb0 + lane * HD);
            float sa = 0.f, sb = 0.f;
#pragma unroll
            for (int dd = 0; dd < 16; dd += 2) {
                float4 k4 = Krow[dd],     q4 = ((const float4*)q_lds)[dd];
                float4 k5 = Krow[dd + 1], q5 = ((const float4*)q_lds)[dd + 1];
                sa = fmaf(k4.x, q4.x, sa); sa = fmaf(k4.y, q4.y, sa);
                sa = fmaf(k4.z, q4.z, sa); sa = fmaf(k4.w, q4.w, sa);
                sb = fmaf(k5.x, q5.x, sb); sb = fmaf(k5.y, q5.y, sb);
                sb = fmaf(k5.z, q5.z, sb); sb = fmaf(k5.w, q5.w, sb);
            }
            sc0 = sa + sb;
        }
        if (hasb1 && lane <= ll1) {
            const float4* Krow = (const float4*)(Kb1 + lane * HD);
            float sa = 0.f, sb = 0.f;
#pragma unroll
            for (int dd = 0; dd < 16; dd += 2) {
                float4 k4 = Krow[dd],     q4 = ((const float4*)q_lds)[dd];
                float4 k5 = Krow[dd + 1], q5 = ((const float4*)q_lds)[dd + 1];
                sa = fmaf(k4.x, q4.x, sa); sa = fmaf(k4.y, q4.y, sa);
                sa = fmaf(k4.z, q4.z, sa); sa = fmaf(k4.w, q4.w, sa);
                sb = fmaf(k5.x, q5.x, sb); sb = fmaf(k5.y, q5.y, sb);
                sb = fmaf(k5.z, q5.z, sb); sb = fmaf(k5.w, q5.w, sb);
            }
            sc1 = sa + sb;
        }

        // prefetch V0 rows for valid slots; loads overlap the shuffle reductions
        float4 v0r[16];
#pragma unroll
        for (int j = 0; j < 16; ++j) {
            const int s = sg + 4 * j;
            if (s <= ll0)
                v0r[j] = *(const float4*)&Vb0[s * HD + d4 * 4];
            else
                v0r[j] = make_float4(0.f, 0.f, 0.f, 0.f);
        }

        // single-pass softmax over both blocks (m_ finite: slot nb0*64 valid)
        const float m_ = wave_max64(fmaxf(sc0, sc1));
        const float p0 = __expf(sc0 - m_);   // 0 for masked lanes
        const float p1 = __expf(sc1 - m_);
        lsum = wave_sum64(p0 + p1);
        m = m_;

#pragma unroll
        for (int j = 0; j < 16; ++j) {
            const float ps = __shfl(p0, sg + 4 * j, 64);  // all lanes active
            vacc.x = fmaf(ps, v0r[j].x, vacc.x);
            vacc.y = fmaf(ps, v0r[j].y, vacc.y);
            vacc.z = fmaf(ps, v0r[j].z, vacc.z);
            vacc.w = fmaf(ps, v0r[j].w, vacc.w);
        }
        if (hasb1) {
#pragma unroll
            for (int j = 0; j < 16; ++j) {
                const int s = sg + 4 * j;
                const float ps = __shfl(p1, s, 64);       // all lanes active
                if (s <= ll1) {
                    float4 v4 = *(const float4*)&Vb1[s * HD + d4 * 4];
                    vacc.x = fmaf(ps, v4.x, vacc.x);
                    vacc.y = fmaf(ps, v4.y, vacc.y);
                    vacc.z = fmaf(ps, v4.z, vacc.z);
                    vacc.w = fmaf(ps, v4.w, vacc.w);
                }
            }
        }
    }

    // reduce vacc over the 4 slot subgroups
#pragma unroll
    for (int o = 16; o <= 32; o <<= 1) {
        vacc.x += __shfl_xor(vacc.x, o, 64);
        vacc.y += __shfl_xor(vacc.y, o, 64);
        vacc.z += __shfl_xor(vacc.z, o, 64);
        vacc.w += __shfl_xor(vacc.w, o, 64);
    }
    if (sg == 0) *(float4*)&o_lds[wv][d4 * 4] = vacc;
    if (lane == 0) { ml_lds[wv * 2 + 0] = m; ml_lds[wv * 2 + 1] = lsum; }
    __syncthreads();

    if (wv == 0) {
        const float qk = wave_sum64(qd * knd);   // new-token score (finite)
        float Mf = qk;
#pragma unroll
        for (int w = 0; w < 4; ++w) Mf = fmaxf(Mf, ml_lds[w * 2]);
        float osum = 0.0f, Ls = 0.0f;
#pragma unroll
        for (int w = 0; w < 4; ++w) {
            const float f = __expf(ml_lds[w * 2] - Mf);   // 0 for empty waves
            osum = fmaf(o_lds[w][lane], f, osum);
            Ls   = fmaf(ml_lds[w * 2 + 1], f, Ls);
        }
        const float pn = __expf(qk - Mf);
        osum = fmaf(pn, vnd, osum);
        Ls += pn;
        o_final[lane] = osum / Ls;
    }
    __syncthreads();

    // ---- o-proj tail: out[b][j] += sum_d o_final[d] * Wo[j][h*64+d] ----
    // 5 rows per thread (j = t + i*256), 256B contiguous W-slice per row,
    // fp32 FMA (more precise than the old bf16 MFMA o-proj), relaxed atomics.
    const float4* of4 = (const float4*)o_final;
#pragma unroll
    for (int i = 0; i < 5; ++i) {
        const int j = t + i * 256;
        const float4* wr = (const float4*)(wo + (size_t)j * E + h * HD);
        float sa = 0.f, sb = 0.f;
#pragma unroll
        for (int dd = 0; dd < 16; dd += 2) {
            float4 w4 = wr[dd],     o4 = of4[dd];
            float4 w5 = wr[dd + 1], o5 = of4[dd + 1];
            sa = fmaf(w4.x, o4.x, sa); sa = fmaf(w4.y, o4.y, sa);
            sa = fmaf(w4.z, o4.z, sa); sa = fmaf(w4.w, o4.w, sa);
            sb = fmaf(w5.x, o5.x, sb); sb = fmaf(w5.y, o5.y, sb);
            sb = fmaf(w5.z, o5.z, sb); sb = fmaf(w5.w, o5.w, sb);
        }
        atomicAdd(&out[(size_t)b * E + j], sa + sb);
    }
}

extern "C" void kernel_launch(void* const* d_in, const int* in_sizes, int n_in,
                              void* d_out, int out_size, void* d_ws, size_t ws_size,
                              hipStream_t stream) {
    const float* hidden = (const float*)d_in[0];
    const float* kcache = (const float*)d_in[1];
    const float* vcache = (const float*)d_in[2];
    const float* wq = (const float*)d_in[3];
    const float* bq = (const float*)d_in[4];
    const float* wk = (const float*)d_in[5];
    const float* bk = (const float*)d_in[6];
    const float* wvp = (const float*)d_in[7];
    const float* bv = (const float*)d_in[8];
    const float* wo = (const float*)d_in[9];
    const float* bo = (const float*)d_in[10];
    const int* cpos = (const int*)d_in[11];
    const int* btab = (const int*)d_in[12];
    float* out = (float*)d_out;

    // ws layout: qkv 64x3840 (983 KB; proven safe)
    float* qkv = (float*)d_ws;

    // node 1: fused QKV projection + bias-init of out (stream-ordered)
    qkv_gemm<<<(3 * E) / 16, 256, 0, stream>>>(
        hidden, wq, wk, wvp, bq, bk, bv, qkv, bo, out);
    // node 2: attention + algebraic o-proj (relaxed atomics, no fences)
    attn_oproj<<<NUNIT, 256, 0, stream>>>(
        qkv, kcache, vcache, cpos, btab, wo, out);
}